// Round 8
// baseline (234.272 us; speedup 1.0000x reference)
//
#include <hip/hip_runtime.h>
#include <math.h>

namespace {

constexpr int Himg = 224, Wimg = 224, Cn = 3, Kk = 32;
constexpr int MAXT = 64;
constexpr int WSTRIDE = 512;               // ints per image in tap workspace
constexpr int IMG_F  = Himg * Wimg * Cn;   // 150528 floats per image
constexpr int ROW_F  = Wimg * Cn;          // 672 floats per row
constexpr int ROW_B  = ROW_F * 4;          // 2688 B

// ---- RGBX padded layout: 224 rows x 256 px x 16 B  (row stride 4096 B) ----
constexpr int PR_PX  = 256;
constexpr int PR_B   = PR_PX * 16;         // 4096 B
constexpr int PIMG_B = Himg * PR_B;        // 917504 B per image
constexpr size_t TAPS_BYTES = 128 * WSTRIDE * sizeof(int);  // 256 KiB

constexpr int PADBLK  = Himg * PR_PX / 256;   // 224 blocks/img (pad pass)
constexpr int CONVBLK = Himg * Wimg / 256;    // 196 blocks/img (conv pass)
// conv blocks c in [14,182): all rows y in [15,208) -> no row mask needed
constexpr int FAST_LO = 14, FAST_HI = 182;

// ---- R7 fallback constants ----
constexpr int IN_CH  = 144;
constexpr int ED_CH  = 24;
constexpr int IN_BLK = Himg * IN_CH / 256;    // 126
constexpr int ED_BLK = Himg * ED_CH / 256;    // 21
constexpr int BLK_PER_IMG = IN_BLK + ED_BLK;  // 147
constexpr int FB_FAST_LO = 9, FB_FAST_HI = 117;

typedef float v4  __attribute__((ext_vector_type(4), aligned(4)));
typedef float v4a __attribute__((ext_vector_type(4), aligned(16)));

// ws per-image layout (ints):
// [0]=n [1]=w [2..65]=dky [66..129]=dkx [130..193]=poff(RGBX bytes) [194..257]=xoff(flat bytes)

// ---------------- pre-pass: one tap list per image ----------------
__global__ __launch_bounds__(64)
void build_taps(const float* __restrict__ tbl,
                const int* __restrict__ amt,
                const int* __restrict__ ang,
                int* __restrict__ ws)
{
    const int b   = blockIdx.x;
    const int tid = threadIdx.x;

    __shared__ int   s_cnt;
    __shared__ float s_w;
    __shared__ int   s_dky[MAXT], s_dkx[MAXT];

    if (tid == 0) { s_cnt = 0; s_w = 0.0f; }
    __syncthreads();

    const int a = amt[b];
    // reference-exact numerics (verified absmax 0.0039 in R1-R7)
    const float  rad = (float)ang[b] * (float)(M_PI / 180.0);
    const double rd  = (double)rad;
    const float  cth = (float)cos(rd);
    const float  sth = (float)sin(rd);
    const float  e   = 31.0f;
    const float xoff = __fmul_rn(__fsub_rn(e, __fsub_rn(__fmul_rn(cth, e), __fmul_rn(sth, e))), 0.5f);
    const float yoff = __fmul_rn(__fsub_rn(e, __fadd_rn(__fmul_rn(sth, e), __fmul_rn(cth, e))), 0.5f);

    for (int p = tid; p < Kk * Kk; p += 64) {
        const int   ky = p >> 5, kx = p & 31;
        const float xf = (float)kx, yf = (float)ky;
        const float sx = __fadd_rn(__fsub_rn(__fmul_rn(cth, xf), __fmul_rn(sth, yf)), xoff);
        const float sy = __fadd_rn(__fadd_rn(__fmul_rn(sth, xf), __fmul_rn(cth, yf)), yoff);
        const int ix = (int)rintf(sx);   // round-half-even == jnp.round
        const int iy = (int)rintf(sy);
        if (ix >= 0 && ix < Kk && iy >= 0 && iy < Kk) {
            const float v = tbl[((a * Kk + iy) * Kk + ix) * Cn];
            if (v != 0.0f) {
                const int idx = atomicAdd(&s_cnt, 1);
                if (idx < MAXT) {
                    s_dky[idx] = ky - 15;
                    s_dkx[idx] = kx - 15;
                    s_w = v;                 // benign race: all writers store 1/size
                }
            }
        }
    }
    __syncthreads();

    const int n = min(s_cnt, MAXT);
    int* wsb = ws + b * WSTRIDE;
    if (tid == 0) { wsb[0] = n; wsb[1] = __float_as_int(s_w); }
    for (int i = tid; i < n; i += 64) {
        wsb[2 + i]   = s_dky[i];
        wsb[66 + i]  = s_dkx[i];
        wsb[130 + i] = (s_dky[i] << 12) + (s_dkx[i] << 4);          // RGBX offset
        wsb[194 + i] = s_dky[i] * ROW_B + s_dkx[i] * (int)(Cn * 4); // flat offset (fallback)
    }
}

// ---------------- pad pass: RGBX, horizontal halo only, XCD-pinned ----------------
__global__ __launch_bounds__(256)
void pad_rgbx(const float* __restrict__ x, float* __restrict__ pad, int B)
{
    const int L = blockIdx.x, tid = threadIdx.x;
    int b, c;
    if (B == 128) {
        const int xcd = L & 7;
        const int j   = L >> 3;
        const int g   = j / PADBLK;
        c = j - g * PADBLK; b = g * 8 + xcd;
    } else { b = L / PADBLK; c = L - b * PADBLK; }

    const int p  = c * 256 + tid;       // [0, 224*256)
    const int y  = p >> 8;
    const int px = p & 255;
    const int sx = px - 16;
    const bool ok = (unsigned)sx < (unsigned)Wimg;

    const float* s = x + (size_t)b * IMG_F + ((size_t)y * Wimg + (ok ? sx : 0)) * Cn;
    const float m  = ok ? 1.0f : 0.0f;
    const float v0 = s[0], v1 = s[1], v2 = s[2];

    v4a* d = (v4a*)((char*)pad + (size_t)b * PIMG_B + (size_t)y * PR_B + ((size_t)px << 4));
    *d = v4a{v0 * m, v1 * m, v2 * m, 0.0f};
}

// ---------------- conv: RGBX, 1 px/thread, 16B-aligned contiguous loads ----------------
__global__ __launch_bounds__(256)
void blur_rgbx(const float* __restrict__ pad,
               const int* __restrict__ ws,
               float* __restrict__ out,
               int B)
{
    const int L = blockIdx.x, tid = threadIdx.x;
    int b, c;
    if (B == 128) {
        const int xcd = L & 7;
        const int j   = L >> 3;
        const int g   = j / CONVBLK;
        c = j - g * CONVBLK; b = g * 8 + xcd;
    } else { b = L / CONVBLK; c = L - b * CONVBLK; }

    __shared__ int shNW[2];
    __shared__ int s_dky[MAXT], s_poff[MAXT];
    const int* wsb = ws + b * WSTRIDE;
    if (tid < 2)    shNW[tid] = wsb[tid];
    if (tid < MAXT) { s_dky[tid] = wsb[2 + tid]; s_poff[tid] = wsb[130 + tid]; }
    __syncthreads();

    const int   n = shNW[0];
    const float w = __int_as_float(shNW[1]);

    const int p  = c * 256 + tid;       // [0, 224*224)
    const int y  = p / 224;
    const int px = p - y * 224;

    const char* base = (const char*)pad + (size_t)b * PIMG_B
                     + (size_t)y * PR_B + ((size_t)(px + 16) << 4);

    float a0 = 0.0f, a1 = 0.0f, a2 = 0.0f;

    if (c >= FAST_LO && c < FAST_HI) {
        // fast path: all rows in-bounds, unroll 4 (4 aligned loads in flight)
        int i = 0;
        for (; i + 4 <= n; i += 4) {
            const v4 f0 = *(const v4*)(base + s_poff[i]);
            const v4 f1 = *(const v4*)(base + s_poff[i + 1]);
            const v4 f2 = *(const v4*)(base + s_poff[i + 2]);
            const v4 f3 = *(const v4*)(base + s_poff[i + 3]);
            a0 += f0.x; a1 += f0.y; a2 += f0.z;
            a0 += f1.x; a1 += f1.y; a2 += f1.z;
            a0 += f2.x; a1 += f2.y; a2 += f2.z;
            a0 += f3.x; a1 += f3.y; a2 += f3.z;
        }
        for (; i < n; ++i) {
            const v4 f = *(const v4*)(base + s_poff[i]);
            a0 += f.x; a1 += f.y; a2 += f.z;
        }
    } else {
        // y-edge blocks: branchless row mask, identical aligned vector loads
        for (int i = 0; i < n; ++i) {
            const int  row = y + s_dky[i];
            const bool ok  = (unsigned)row < (unsigned)Himg;
            const int  off = ok ? s_poff[i] : 0;     // own px, always valid
            const float m  = ok ? 1.0f : 0.0f;
            const v4 f = *(const v4*)(base + off);
            a0 += m * f.x; a1 += m * f.y; a2 += m * f.z;
        }
    }

    float* o = out + (size_t)b * IMG_F + (size_t)p * 3;
    o[0] = a0 * w; o[1] = a1 * w; o[2] = a2 * w;
}

// ---------------- R7 fallback conv (proven, direct from x) ----------------
__global__ __launch_bounds__(256)
void blur_direct(const float* __restrict__ x,
                 const int* __restrict__ ws,
                 float* __restrict__ out,
                 int B)
{
    const int tid = threadIdx.x;
    const int L   = blockIdx.x;

    int b, c;
    if (B == 128) {
        const int xcd = L & 7;
        const int j   = L >> 3;
        const int g   = j / BLK_PER_IMG;
        c = j - g * BLK_PER_IMG;
        b = g * 8 + xcd;
    } else { b = L / BLK_PER_IMG; c = L - b * BLK_PER_IMG; }

    __shared__ int shNW[2];
    __shared__ int s_dky[MAXT], s_dkx[MAXT], s_xoff[MAXT];
    const int* wsb = ws + b * WSTRIDE;
    if (tid < 2)    shNW[tid] = wsb[tid];
    if (tid < MAXT) {
        s_dky[tid]  = wsb[2 + tid];
        s_dkx[tid]  = wsb[66 + tid];
        s_xoff[tid] = wsb[194 + tid];
    }
    __syncthreads();

    const int   n = shNW[0];
    const float w = __int_as_float(shNW[1]);
    const float* xb = x + (size_t)b * IMG_F;

    if (c < IN_BLK) {
        const int ii = c * 256 + tid;
        const int y  = ii / IN_CH;
        const int k  = ii - y * IN_CH + 12;
        const int fbase = y * ROW_F + 4 * k;
        const char* base = (const char*)xb + (size_t)fbase * 4;

        float a0 = 0.0f, a1 = 0.0f, a2 = 0.0f, a3 = 0.0f;

        if (c >= FB_FAST_LO && c < FB_FAST_HI) {
            int i = 0;
            for (; i + 4 <= n; i += 4) {
                const v4 f0 = *(const v4*)(base + s_xoff[i]);
                const v4 f1 = *(const v4*)(base + s_xoff[i + 1]);
                const v4 f2 = *(const v4*)(base + s_xoff[i + 2]);
                const v4 f3 = *(const v4*)(base + s_xoff[i + 3]);
                a0 += f0.x; a1 += f0.y; a2 += f0.z; a3 += f0.w;
                a0 += f1.x; a1 += f1.y; a2 += f1.z; a3 += f1.w;
                a0 += f2.x; a1 += f2.y; a2 += f2.z; a3 += f2.w;
                a0 += f3.x; a1 += f3.y; a2 += f3.z; a3 += f3.w;
            }
            for (; i < n; ++i) {
                const v4 f = *(const v4*)(base + s_xoff[i]);
                a0 += f.x; a1 += f.y; a2 += f.z; a3 += f.w;
            }
        } else {
            for (int i = 0; i < n; ++i) {
                const int  row = y + s_dky[i];
                const bool ok  = (unsigned)row < (unsigned)Himg;
                const int  off = ok ? s_xoff[i] : 0;
                const float m  = ok ? 1.0f : 0.0f;
                const v4 f = *(const v4*)(base + off);
                a0 += m * f.x; a1 += m * f.y; a2 += m * f.z; a3 += m * f.w;
            }
        }

        float* o = out + (size_t)b * IMG_F + fbase;
        __builtin_nontemporal_store(v4a{a0 * w, a1 * w, a2 * w, a3 * w}, (v4a*)o);
    } else {
        const int ee = (c - IN_BLK) * 256 + tid;
        const int y  = ee / ED_CH;
        const int j  = ee - y * ED_CH;
        const int k  = (j < 12) ? j : (j + 144);
        const int fd0 = 4 * k;

        float acc[4] = {0.0f, 0.0f, 0.0f, 0.0f};
        for (int i = 0; i < n; ++i) {
            const int  row = y + s_dky[i];
            const bool rok = (unsigned)row < (unsigned)Himg;
            const int  s0  = fd0 + 3 * s_dkx[i];
            const int  ob  = row * ROW_F + s0;
#pragma unroll
            for (int q = 0; q < 4; ++q) {
                const bool ok  = rok & ((unsigned)(s0 + q) < (unsigned)ROW_F);
                const int  off = ok ? (ob + q) : 0;
                const float v  = xb[off];
                acc[q] += ok ? v : 0.0f;
            }
        }

        float* o = out + (size_t)b * IMG_F + (size_t)y * ROW_F + fd0;
        __builtin_nontemporal_store(
            v4a{acc[0] * w, acc[1] * w, acc[2] * w, acc[3] * w}, (v4a*)o);
    }
}

}  // namespace

extern "C" void kernel_launch(void* const* d_in, const int* in_sizes, int n_in,
                              void* d_out, int out_size, void* d_ws, size_t ws_size,
                              hipStream_t stream) {
    const float* x   = (const float*)d_in[0];
    const float* tbl = (const float*)d_in[1];
    const int*   amt = (const int*)d_in[2];
    const int*   ang = (const int*)d_in[3];
    float*       out = (float*)d_out;
    int*         ws  = (int*)d_ws;

    const int B = in_sizes[2];  // 128

    build_taps<<<B, 64, 0, stream>>>(tbl, amt, ang, ws);

    const size_t need = TAPS_BYTES + (size_t)B * PIMG_B;
    if (ws_size >= need) {
        float* pad = (float*)((char*)d_ws + TAPS_BYTES);
        pad_rgbx<<<B * PADBLK, 256, 0, stream>>>(x, pad, B);
        blur_rgbx<<<B * CONVBLK, 256, 0, stream>>>(pad, ws, out, B);
    } else {
        blur_direct<<<B * BLK_PER_IMG, 256, 0, stream>>>(x, ws, out, B);
    }
}